// Round 1
// baseline (715.970 us; speedup 1.0000x reference)
//
#include <hip/hip_runtime.h>
#include <math.h>

// Problem dims (fixed by setup_inputs): values [N,B,T,H] fp32
#define N 8
#define B 4
#define T 2048
#define H 2048

static constexpr float EPS = 1e-6f;
// scale = sqrt(H) * TEMPERATURE
static constexpr float INV_SCALE = 1.0f / 45.25483399593904f;

// ---------------- pre-kernel: qb[n] = dot(w_query[pos], key_pos_bias[n]) ----
__global__ __launch_bounds__(256) void qb_kernel(
    const float* __restrict__ w_query,
    const float* __restrict__ key_pos_bias,
    const int* __restrict__ position,
    float* __restrict__ qb /* 8 floats in d_ws */) {
    const int pos = *position;
    const float* q = w_query + (size_t)pos * H;
    const int tid = threadIdx.x;
    float part[N];
#pragma unroll
    for (int n = 0; n < N; ++n) part[n] = 0.f;
    for (int h = tid; h < H; h += 256) {
        const float qv = q[h];
#pragma unroll
        for (int n = 0; n < N; ++n)
            part[n] += qv * key_pos_bias[(size_t)n * H + h];
    }
#pragma unroll
    for (int n = 0; n < N; ++n) {
#pragma unroll
        for (int off = 32; off; off >>= 1)
            part[n] += __shfl_xor(part[n], off);
    }
    __shared__ float red[4][N];
    const int wave = tid >> 6, lane = tid & 63;
    if (lane == 0) {
#pragma unroll
        for (int n = 0; n < N; ++n) red[wave][n] = part[n];
    }
    __syncthreads();
    if (tid < N)
        qb[tid] = red[0][tid] + red[1][tid] + red[2][tid] + red[3][tid];
}

// ---------------- main fused kernel: one block per (b,t) --------------------
__global__ __launch_bounds__(256) void router_kernel(
    const float* __restrict__ values,
    const float* __restrict__ w_query,
    const int* __restrict__ position,
    const float* __restrict__ qb,
    float* __restrict__ routed,      // [B,T,H]
    float* __restrict__ alpha_out) { // [B,T,N]
    const int tid = threadIdx.x;
    const int bt  = blockIdx.x;
    const int b   = bt >> 11;          // T = 2048
    const int t   = bt & (T - 1);
    const int h0  = tid * 8;           // 256 threads * 8 = 2048 = H

    const int pos = *position;
    const float* qp = w_query + (size_t)pos * H + h0;
    const float4 q0 = *(const float4*)(qp);
    const float4 q1 = *(const float4*)(qp + 4);

    const float* vbase = values + ((size_t)b * T + t) * H + h0;

    float v[N][8];
    float ss[N], qd[N];
#pragma unroll
    for (int n = 0; n < N; ++n) {
        const float4* p = (const float4*)(vbase + (size_t)n * ((size_t)B * T * H));
        const float4 a0 = p[0];
        const float4 a1 = p[1];
        v[n][0] = a0.x; v[n][1] = a0.y; v[n][2] = a0.z; v[n][3] = a0.w;
        v[n][4] = a1.x; v[n][5] = a1.y; v[n][6] = a1.z; v[n][7] = a1.w;
        ss[n] = a0.x*a0.x + a0.y*a0.y + a0.z*a0.z + a0.w*a0.w
              + a1.x*a1.x + a1.y*a1.y + a1.z*a1.z + a1.w*a1.w;
        qd[n] = q0.x*a0.x + q0.y*a0.y + q0.z*a0.z + q0.w*a0.w
              + q1.x*a1.x + q1.y*a1.y + q1.z*a1.z + q1.w*a1.w;
    }

    // 64-lane butterfly reduction of 16 quantities
#pragma unroll
    for (int n = 0; n < N; ++n) {
#pragma unroll
        for (int off = 32; off; off >>= 1) {
            ss[n] += __shfl_xor(ss[n], off);
            qd[n] += __shfl_xor(qd[n], off);
        }
    }

    __shared__ float red[4][2 * N];
    __shared__ float tot[2 * N];
    const int wave = tid >> 6, lane = tid & 63;
    if (lane == 0) {
#pragma unroll
        for (int n = 0; n < N; ++n) {
            red[wave][n]     = ss[n];
            red[wave][N + n] = qd[n];
        }
    }
    __syncthreads();
    if (tid < 2 * N)
        tot[tid] = red[0][tid] + red[1][tid] + red[2][tid] + red[3][tid];
    __syncthreads();

    // softmax over n (computed redundantly by all threads; 8 entries)
    float sc[N];
    float m = -INFINITY;
#pragma unroll
    for (int n = 0; n < N; ++n) {
        const float inv = rsqrtf(tot[n] * (1.0f / (float)H) + EPS);
        sc[n] = (inv * tot[N + n] + qb[n]) * INV_SCALE;
        m = fmaxf(m, sc[n]);
    }
    float ssum = 0.f;
    float alpha[N];
#pragma unroll
    for (int n = 0; n < N; ++n) {
        alpha[n] = __expf(sc[n] - m);
        ssum += alpha[n];
    }
    const float rs = 1.0f / ssum;
#pragma unroll
    for (int n = 0; n < N; ++n) alpha[n] *= rs;

    // routed[b,t,h] = sum_n alpha[n] * v[n][h]
    float o[8];
#pragma unroll
    for (int j = 0; j < 8; ++j) {
        float acc = 0.f;
#pragma unroll
        for (int n = 0; n < N; ++n) acc += alpha[n] * v[n][j];
        o[j] = acc;
    }
    float* op = routed + ((size_t)b * T + t) * H + h0;
    *(float4*)(op)     = make_float4(o[0], o[1], o[2], o[3]);
    *(float4*)(op + 4) = make_float4(o[4], o[5], o[6], o[7]);

    if (tid == 0) {
        float* ap = alpha_out + ((size_t)b * T + t) * N;
        *(float4*)(ap)     = make_float4(alpha[0], alpha[1], alpha[2], alpha[3]);
        *(float4*)(ap + 4) = make_float4(alpha[4], alpha[5], alpha[6], alpha[7]);
    }
}

extern "C" void kernel_launch(void* const* d_in, const int* in_sizes, int n_in,
                              void* d_out, int out_size, void* d_ws, size_t ws_size,
                              hipStream_t stream) {
    const float* values   = (const float*)d_in[0];
    const float* w_query  = (const float*)d_in[1];
    const float* bias     = (const float*)d_in[2];
    const int*   position = (const int*)d_in[3];
    float* out = (float*)d_out;
    float* qb  = (float*)d_ws;

    qb_kernel<<<1, 256, 0, stream>>>(w_query, bias, position, qb);
    router_kernel<<<B * T, 256, 0, stream>>>(
        values, w_query, position, qb,
        out, out + (size_t)B * T * H);
}

// Round 4
// 684.000 us; speedup vs baseline: 1.0467x; 1.0467x over previous
//
#include <hip/hip_runtime.h>
#include <math.h>

// Problem dims (fixed by setup_inputs): values [N,B,T,H] fp32
#define N 8
#define B 4
#define T 2048
#define H 2048

static constexpr float EPS = 1e-6f;
// scale = sqrt(H) * TEMPERATURE
static constexpr float INV_SCALE = 1.0f / 45.25483399593904f;

// native vector type accepted by __builtin_nontemporal_*
typedef float floatx4 __attribute__((ext_vector_type(4)));

// ---------------- pre-kernel: qb[n] = dot(w_query[pos], key_pos_bias[n]) ----
__global__ __launch_bounds__(256) void qb_kernel(
    const float* __restrict__ w_query,
    const float* __restrict__ key_pos_bias,
    const int* __restrict__ position,
    float* __restrict__ qb /* 8 floats in d_ws */) {
    const int pos = *position;
    const float* q = w_query + (size_t)pos * H;
    const int tid = threadIdx.x;
    float part[N];
#pragma unroll
    for (int n = 0; n < N; ++n) part[n] = 0.f;
    for (int h = tid; h < H; h += 256) {
        const float qv = q[h];
#pragma unroll
        for (int n = 0; n < N; ++n)
            part[n] += qv * key_pos_bias[(size_t)n * H + h];
    }
#pragma unroll
    for (int n = 0; n < N; ++n) {
#pragma unroll
        for (int off = 32; off; off >>= 1)
            part[n] += __shfl_xor(part[n], off);
    }
    __shared__ float red[4][N];
    const int wave = tid >> 6, lane = tid & 63;
    if (lane == 0) {
#pragma unroll
        for (int n = 0; n < N; ++n) red[wave][n] = part[n];
    }
    __syncthreads();
    if (tid < N)
        qb[tid] = red[0][tid] + red[1][tid] + red[2][tid] + red[3][tid];
}

// ---------------- main fused kernel: one block (512 thr) per (b,t) ----------
__global__ __launch_bounds__(512, 6) void router_kernel(
    const float* __restrict__ values,
    const float* __restrict__ w_query,
    const int* __restrict__ position,
    const float* __restrict__ qb,
    float* __restrict__ routed,      // [B,T,H]
    float* __restrict__ alpha_out) { // [B,T,N]
    const int tid = threadIdx.x;
    const int bt  = blockIdx.x;
    const int b   = bt >> 11;          // T = 2048
    const int t   = bt & (T - 1);
    const int h0  = tid * 4;           // 512 threads * 4 = 2048 = H

    const int pos = *position;
    const floatx4 q = *(const floatx4*)(w_query + (size_t)pos * H + h0);

    const float* vbase = values + ((size_t)b * T + t) * H + h0;
    const size_t nstride = (size_t)B * T * H;

    floatx4 v[N];
    float ss[N], qd[N];
#pragma unroll
    for (int n = 0; n < N; ++n) {
        const floatx4 a = __builtin_nontemporal_load(
            (const floatx4*)(vbase + (size_t)n * nstride));
        v[n] = a;
        ss[n] = a.x*a.x + a.y*a.y + a.z*a.z + a.w*a.w;
        qd[n] = q.x*a.x + q.y*a.y + q.z*a.z + q.w*a.w;
    }

    // 64-lane butterfly reduction of 16 quantities
#pragma unroll
    for (int n = 0; n < N; ++n) {
#pragma unroll
        for (int off = 32; off; off >>= 1) {
            ss[n] += __shfl_xor(ss[n], off);
            qd[n] += __shfl_xor(qd[n], off);
        }
    }

    __shared__ float red[8][2 * N];
    __shared__ float tot[2 * N];
    const int wave = tid >> 6, lane = tid & 63;
    if (lane == 0) {
#pragma unroll
        for (int n = 0; n < N; ++n) {
            red[wave][n]     = ss[n];
            red[wave][N + n] = qd[n];
        }
    }
    __syncthreads();
    if (tid < 2 * N) {
        float s = 0.f;
#pragma unroll
        for (int w = 0; w < 8; ++w) s += red[w][tid];
        tot[tid] = s;
    }
    __syncthreads();

    // softmax over n (computed redundantly by all threads; 8 entries)
    float sc[N];
    float m = -INFINITY;
#pragma unroll
    for (int n = 0; n < N; ++n) {
        const float inv = rsqrtf(tot[n] * (1.0f / (float)H) + EPS);
        sc[n] = (inv * tot[N + n] + qb[n]) * INV_SCALE;
        m = fmaxf(m, sc[n]);
    }
    float ssum = 0.f;
    float alpha[N];
#pragma unroll
    for (int n = 0; n < N; ++n) {
        alpha[n] = __expf(sc[n] - m);
        ssum += alpha[n];
    }
    const float rs = 1.0f / ssum;
#pragma unroll
    for (int n = 0; n < N; ++n) alpha[n] *= rs;

    // routed[b,t,h] = sum_n alpha[n] * v[n][h]
    floatx4 o;
    o.x = 0.f; o.y = 0.f; o.z = 0.f; o.w = 0.f;
#pragma unroll
    for (int n = 0; n < N; ++n) {
        o.x += alpha[n] * v[n].x;
        o.y += alpha[n] * v[n].y;
        o.z += alpha[n] * v[n].z;
        o.w += alpha[n] * v[n].w;
    }
    __builtin_nontemporal_store(o, (floatx4*)(routed + ((size_t)b * T + t) * H + h0));

    if (tid == 0) {
        float* ap = alpha_out + ((size_t)b * T + t) * N;
        floatx4 a0 = { alpha[0], alpha[1], alpha[2], alpha[3] };
        floatx4 a1 = { alpha[4], alpha[5], alpha[6], alpha[7] };
        *(floatx4*)(ap)     = a0;
        *(floatx4*)(ap + 4) = a1;
    }
}

extern "C" void kernel_launch(void* const* d_in, const int* in_sizes, int n_in,
                              void* d_out, int out_size, void* d_ws, size_t ws_size,
                              hipStream_t stream) {
    const float* values   = (const float*)d_in[0];
    const float* w_query  = (const float*)d_in[1];
    const float* bias     = (const float*)d_in[2];
    const int*   position = (const int*)d_in[3];
    float* out = (float*)d_out;
    float* qb  = (float*)d_ws;

    qb_kernel<<<1, 256, 0, stream>>>(w_query, bias, position, qb);
    router_kernel<<<B * T, 512, 0, stream>>>(
        values, w_query, position, qb,
        out, out + (size_t)B * T * H);
}

// Round 6
// 677.377 us; speedup vs baseline: 1.0570x; 1.0098x over previous
//
#include <hip/hip_runtime.h>
#include <math.h>

// Problem dims (fixed by setup_inputs): values [N,B,T,H] fp32
#define N 8
#define B 4
#define T 2048
#define H 2048
#define THREADS 512

static constexpr float EPS = 1e-6f;
// scale = sqrt(H) * TEMPERATURE
static constexpr float INV_SCALE = 1.0f / 45.25483399593904f;

// native vector type accepted by __builtin_nontemporal_*
typedef float floatx4 __attribute__((ext_vector_type(4)));
typedef float floatx2 __attribute__((ext_vector_type(2)));

// ---------------- pre-kernel: qb[n] = dot(w_query[pos], key_pos_bias[n]) ----
__global__ __launch_bounds__(256) void qb_kernel(
    const float* __restrict__ w_query,
    const float* __restrict__ key_pos_bias,
    const int* __restrict__ position,
    float* __restrict__ qb /* 8 floats in d_ws */) {
    const int pos = *position;
    const int tid = threadIdx.x;
    const int h0  = tid * 8;                 // 256 threads * 8 = 2048 = H
    const float* qp = w_query + (size_t)pos * H + h0;
    const floatx4 q0 = *(const floatx4*)(qp);
    const floatx4 q1 = *(const floatx4*)(qp + 4);

    float part[N];
#pragma unroll
    for (int n = 0; n < N; ++n) {
        const float* bp = key_pos_bias + (size_t)n * H + h0;
        const floatx4 b0 = *(const floatx4*)(bp);
        const floatx4 b1 = *(const floatx4*)(bp + 4);
        part[n] = q0.x*b0.x + q0.y*b0.y + q0.z*b0.z + q0.w*b0.w
                + q1.x*b1.x + q1.y*b1.y + q1.z*b1.z + q1.w*b1.w;
    }
#pragma unroll
    for (int n = 0; n < N; ++n) {
#pragma unroll
        for (int off = 32; off; off >>= 1)
            part[n] += __shfl_xor(part[n], off);
    }
    __shared__ float red[4][N];
    const int wave = tid >> 6, lane = tid & 63;
    if (lane == 0) {
#pragma unroll
        for (int n = 0; n < N; ++n) red[wave][n] = part[n];
    }
    __syncthreads();
    if (tid < N)
        qb[tid] = red[0][tid] + red[1][tid] + red[2][tid] + red[3][tid];
}

// ---------------- main fused kernel: one block (512 thr) per (b,t) ----------
// LDS-transpose reduce instead of 96-shuffle butterfly: each thread writes its
// 16 partials (ss[n], qd[n] interleaved) to part[tid][18]; wave w then reduces
// quantity-pair n=w with 8 ds_read_b64 + 12 shuffles.
__global__ __launch_bounds__(THREADS, 6) void router_kernel(
    const float* __restrict__ values,
    const float* __restrict__ w_query,
    const int* __restrict__ position,
    const float* __restrict__ qb,
    float* __restrict__ routed,      // [B,T,H]
    float* __restrict__ alpha_out) { // [B,T,N]
    const int tid = threadIdx.x;
    const int bt  = blockIdx.x;
    const int b   = bt >> 11;          // T = 2048
    const int t   = bt & (T - 1);
    const int h0  = tid * 4;           // 512 threads * 4 = 2048 = H

    const int pos = *position;
    const floatx4 q = *(const floatx4*)(w_query + (size_t)pos * H + h0);

    const float* vbase = values + ((size_t)b * T + t) * H + h0;
    const size_t nstride = (size_t)B * T * H;

    __shared__ float part[THREADS][18];  // row stride 18 floats (8B-aligned pairs)
    __shared__ float tot[2 * N];

    floatx4 v[N];
#pragma unroll
    for (int n = 0; n < N; ++n) {
        const floatx4 a = __builtin_nontemporal_load(
            (const floatx4*)(vbase + (size_t)n * nstride));
        v[n] = a;
        const float ss = a.x*a.x + a.y*a.y + a.z*a.z + a.w*a.w;
        const float qd = q.x*a.x + q.y*a.y + q.z*a.z + q.w*a.w;
        *(floatx2*)&part[tid][2 * n] = floatx2{ss, qd};
    }
    __syncthreads();

    // wave w reduces (ss[w], qd[w]) over all 512 threads
    const int wave = tid >> 6, lane = tid & 63;
    {
        float ssum = 0.f, qsum = 0.f;
#pragma unroll
        for (int k = 0; k < 8; ++k) {
            const floatx2 p = *(const floatx2*)&part[lane + 64 * k][2 * wave];
            ssum += p.x; qsum += p.y;
        }
#pragma unroll
        for (int off = 32; off; off >>= 1) {
            ssum += __shfl_xor(ssum, off);
            qsum += __shfl_xor(qsum, off);
        }
        if (lane == 0) {
            tot[wave]     = ssum;
            tot[N + wave] = qsum;
        }
    }
    __syncthreads();

    // softmax over n (computed redundantly by all threads; 8 entries)
    float sc[N];
    float m = -INFINITY;
#pragma unroll
    for (int n = 0; n < N; ++n) {
        const float inv = rsqrtf(tot[n] * (1.0f / (float)H) + EPS);
        sc[n] = (inv * tot[N + n] + qb[n]) * INV_SCALE;
        m = fmaxf(m, sc[n]);
    }
    float ssum = 0.f;
    float alpha[N];
#pragma unroll
    for (int n = 0; n < N; ++n) {
        alpha[n] = __expf(sc[n] - m);
        ssum += alpha[n];
    }
    const float rs = 1.0f / ssum;
#pragma unroll
    for (int n = 0; n < N; ++n) alpha[n] *= rs;

    // routed[b,t,h] = sum_n alpha[n] * v[n][h]
    floatx4 o;
    o.x = 0.f; o.y = 0.f; o.z = 0.f; o.w = 0.f;
#pragma unroll
    for (int n = 0; n < N; ++n) {
        o.x += alpha[n] * v[n].x;
        o.y += alpha[n] * v[n].y;
        o.z += alpha[n] * v[n].z;
        o.w += alpha[n] * v[n].w;
    }
    __builtin_nontemporal_store(o, (floatx4*)(routed + ((size_t)b * T + t) * H + h0));

    if (tid == 0) {
        float* ap = alpha_out + ((size_t)b * T + t) * N;
        floatx4 a0 = { alpha[0], alpha[1], alpha[2], alpha[3] };
        floatx4 a1 = { alpha[4], alpha[5], alpha[6], alpha[7] };
        *(floatx4*)(ap)     = a0;
        *(floatx4*)(ap + 4) = a1;
    }
}

extern "C" void kernel_launch(void* const* d_in, const int* in_sizes, int n_in,
                              void* d_out, int out_size, void* d_ws, size_t ws_size,
                              hipStream_t stream) {
    const float* values   = (const float*)d_in[0];
    const float* w_query  = (const float*)d_in[1];
    const float* bias     = (const float*)d_in[2];
    const int*   position = (const int*)d_in[3];
    float* out = (float*)d_out;
    float* qb  = (float*)d_ws;

    qb_kernel<<<1, 256, 0, stream>>>(w_query, bias, position, qb);
    router_kernel<<<B * T, THREADS, 0, stream>>>(
        values, w_query, position, qb,
        out, out + (size_t)B * T * H);
}